// Round 4
// baseline (1221.105 us; speedup 1.0000x reference)
//
#include <hip/hip_runtime.h>

#define N_NODE 50000
#define N_EDGE 400000
#define INF    128

// segment tiling (32 rows/tile), boundaries are compile-time: 10000 / 20000 / 50000
#define TILES0 313
#define TILES1 313
#define TILES2 938
#define NTILES 1564

__device__ __forceinline__ void seg_decode(int b, int& ty, int& base, int& nrows) {
  if (b < TILES0)            { ty = 0; base = b * 32;                      nrows = 10000 - base; }
  else if (b < TILES0+TILES1){ ty = 1; base = 10000 + (b - TILES0) * 32;   nrows = 20000 - base; }
  else                       { ty = 2; base = 20000 + (b - TILES0-TILES1)*32; nrows = 50000 - base; }
  if (nrows > 32) nrows = 32;
}

__device__ __forceinline__ float blo(unsigned u) { return __uint_as_float(u << 16); }
__device__ __forceinline__ float bhi(unsigned u) { return __uint_as_float(u & 0xffff0000u); }
// pack two f32 -> bf16x2 (RNE), lo = even dim, hi = odd dim
__device__ __forceinline__ unsigned bpack(float lo, float hi) {
  unsigned a = __float_as_uint(lo), b = __float_as_uint(hi);
  a = (a + 0x7fffu + ((a >> 16) & 1u)) >> 16;
  b = (b + 0x7fffu + ((b >> 16) & 1u)) & 0xffff0000u;
  return a | b;
}

// ---- concat features into x (= d_out) ------------------------------------
__global__ __launch_bounds__(256) void k_concat(const float* __restrict__ dr,
                                                const float* __restrict__ di,
                                                const float* __restrict__ pr,
                                                float* __restrict__ x) {
  int i = blockIdx.x * 256 + threadIdx.x;      // float4 index
  if (i >= N_NODE * 32) return;
  int row = i >> 5;
  float4 val;
  if (row < 10000)      val = ((const float4*)dr)[i];
  else if (row < 20000) val = ((const float4*)di)[i - 10000*32];
  else                  val = ((const float4*)pr)[i - 20000*32];
  ((float4*)x)[i] = val;
}

// ---- CSR build -----------------------------------------------------------
__global__ __launch_bounds__(256) void k_count(const int* __restrict__ dst, int* __restrict__ deg) {
  int e = blockIdx.x * 256 + threadIdx.x;
  if (e < N_EDGE) atomicAdd(&deg[dst[e]], 1);
}

__global__ __launch_bounds__(1024) void k_scan(const int* __restrict__ deg,
                                               int* __restrict__ off, int* __restrict__ cur) {
  __shared__ int part[1024];
  int t = threadIdx.x;
  int c0 = t * 49;
  int c1 = c0 + 49; if (c1 > N_NODE) c1 = N_NODE;
  int s = 0;
  for (int i = c0; i < c1; ++i) s += deg[i];
  part[t] = s;
  __syncthreads();
  for (int ofs = 1; ofs < 1024; ofs <<= 1) {
    int v = (t >= ofs) ? part[t - ofs] : 0;
    __syncthreads();
    part[t] += v;
    __syncthreads();
  }
  int run = (t == 0) ? 0 : part[t - 1];
  for (int i = c0; i < c1; ++i) { off[i] = run; cur[i] = run; run += deg[i]; }
  if (t == 1023) off[N_NODE] = part[1023];
}

// writes combined edge record est[p] = (src<<2) | etype  (kills one gather hop)
__global__ __launch_bounds__(256) void k_fill(const int* __restrict__ dst,
                                              const int* __restrict__ src,
                                              const int* __restrict__ etp,
                                              int* __restrict__ cur, int* __restrict__ est) {
  int e = blockIdx.x * 256 + threadIdx.x;
  if (e < N_EDGE) {
    int p = atomicAdd(&cur[dst[e]], 1);
    est[p] = (src[e] << 2) | etp[e];
  }
}

// ---- transpose rel_msg: AmT[h][ty][do][di] = rel_msg[h][ty][di][do] ------
__global__ __launch_bounds__(256) void k_trmsg(const float* __restrict__ rm,
                                               float* __restrict__ AmT) {
  int i = blockIdx.x * 256 + threadIdx.x;   // 8192 total
  int di = i & 15, doo = (i >> 4) & 15, ty = (i >> 8) & 3, hh = i >> 10;
  AmT[i] = rm[((hh * 4 + ty) * 16 + di) * 16 + doo];
}

// ---- typed K/Q/V projection; k,v packed interleaved bf16 -----------------
// kvb[n] = 64 x uint2 : elem l = { bf16x2(k[2l],k[2l+1]), bf16x2(v[2l],v[2l+1]) }
__global__ __launch_bounds__(256) void k_qkv(const float* __restrict__ x,
                                             const float* __restrict__ Wk,
                                             const float* __restrict__ Wq,
                                             const float* __restrict__ Wv,
                                             uint2* __restrict__ kvb,
                                             float* __restrict__ qb) {
  __shared__ float xs[32][128];
  int ty, base, nrows;
  seg_decode(blockIdx.x, ty, base, nrows);
  int t = threadIdx.x;
#pragma unroll
  for (int it = 0; it < 4; ++it) {
    int idx4 = t + it * 256;
    int row = idx4 >> 5, c4 = idx4 & 31;
    float4 val = make_float4(0.f, 0.f, 0.f, 0.f);
    if (row < nrows) val = ((const float4*)(x + (size_t)(base + row) * INF))[c4];
    ((float4*)&xs[row][0])[c4] = val;
  }
  __syncthreads();
  int o = t & 127, g = t >> 7;
  float ak[16], aq[16], av[16];
#pragma unroll
  for (int j = 0; j < 16; ++j) { ak[j] = 0.f; aq[j] = 0.f; av[j] = 0.f; }
  const float* WK = Wk + ty * 16384;
  const float* WQ = Wq + ty * 16384;
  const float* WV = Wv + ty * 16384;
  for (int i0 = 0; i0 < 32; ++i0) {
    float wk[4], wq[4], wv[4];
#pragma unroll
    for (int di = 0; di < 4; ++di) {
      int i = i0 * 4 + di;
      wk[di] = WK[i * 128 + o];
      wq[di] = WQ[i * 128 + o];
      wv[di] = WV[i * 128 + o];
    }
#pragma unroll
    for (int j = 0; j < 16; ++j) {
      float4 x4 = ((const float4*)&xs[g * 16 + j][0])[i0];
      ak[j] += x4.x * wk[0] + x4.y * wk[1] + x4.z * wk[2] + x4.w * wk[3];
      aq[j] += x4.x * wq[0] + x4.y * wq[1] + x4.z * wq[2] + x4.w * wq[3];
      av[j] += x4.x * wv[0] + x4.y * wv[1] + x4.z * wv[2] + x4.w * wv[3];
    }
  }
#pragma unroll
  for (int j = 0; j < 16; ++j) {
    int row = g * 16 + j;
    float akn = __shfl_xor(ak[j], 1);   // neighbor column value (same row)
    float avn = __shfl_xor(av[j], 1);
    if (row < nrows) {
      size_t p = (size_t)(base + row);
      qb[p * INF + o] = aq[j];
      if ((o & 1) == 0)
        kvb[p * 64 + (o >> 1)] = make_uint2(bpack(ak[j], akn), bpack(av[j], avn));
    }
  }
}

// ---- fused attention: logits + edge-softmax + aggregation ---------------
// 1 wave per dst node, 4 nodes per 256-thread block, no __syncthreads.
// lane l: head h = l>>3, j = l&7 -> dims (h*16+2j, h*16+2j+1).
// 4 independent online-softmax streams (edges i,i+1,i+2,i+3) merged at end.
__global__ __launch_bounds__(256) void k_fused(const uint2* __restrict__ kvb,
                                               const float* __restrict__ qb,
                                               const int* __restrict__ off,
                                               const int* __restrict__ est,
                                               const float* __restrict__ rel_att,
                                               const float* __restrict__ AmT,
                                               const float* __restrict__ pri,
                                               float* __restrict__ hb) {
  __shared__ float accs[4][4][128];
  int w = threadIdx.x >> 6, l = threadIdx.x & 63;
  int n = blockIdx.x * 4 + w;
  int h = l >> 3, j = l & 7;

  int o0 = off[n], o1 = off[n + 1];

  // q head fragment direct from global (L1 broadcast across the 8 lanes/head)
  const float4* q4p = (const float4*)(qb + (size_t)n * INF);
  float4 q40 = q4p[h * 4 + 0], q41 = q4p[h * 4 + 1];
  float4 q42 = q4p[h * 4 + 2], q43 = q4p[h * 4 + 3];
  float4 prh = ((const float4*)pri)[h];

  // qa[ty] = (pri[h,ty]/4) * rel_att[h,ty] . q[n]  for this lane's 2 dims
  float2 qa0, qa1, qa2, qa3;
#define QA_COMPUTE(QA, TY, PRSC) { \
    float ax = 0.f, ay = 0.f; \
    const float4* Ar = (const float4*)(rel_att + ((h * 4 + (TY)) * 16) * 16); \
    float4 a0, a1; \
    a0 = Ar[(2*j)*4+0]; a1 = Ar[(2*j+1)*4+0]; \
    ax += a0.x*q40.x + a0.y*q40.y + a0.z*q40.z + a0.w*q40.w; \
    ay += a1.x*q40.x + a1.y*q40.y + a1.z*q40.z + a1.w*q40.w; \
    a0 = Ar[(2*j)*4+1]; a1 = Ar[(2*j+1)*4+1]; \
    ax += a0.x*q41.x + a0.y*q41.y + a0.z*q41.z + a0.w*q41.w; \
    ay += a1.x*q41.x + a1.y*q41.y + a1.z*q41.z + a1.w*q41.w; \
    a0 = Ar[(2*j)*4+2]; a1 = Ar[(2*j+1)*4+2]; \
    ax += a0.x*q42.x + a0.y*q42.y + a0.z*q42.z + a0.w*q42.w; \
    ay += a1.x*q42.x + a1.y*q42.y + a1.z*q42.z + a1.w*q42.w; \
    a0 = Ar[(2*j)*4+3]; a1 = Ar[(2*j+1)*4+3]; \
    ax += a0.x*q43.x + a0.y*q43.y + a0.z*q43.z + a0.w*q43.w; \
    ay += a1.x*q43.x + a1.y*q43.y + a1.z*q43.z + a1.w*q43.w; \
    QA = make_float2(ax * (PRSC), ay * (PRSC)); }
  QA_COMPUTE(qa0, 0, prh.x * 0.25f)
  QA_COMPUTE(qa1, 1, prh.y * 0.25f)
  QA_COMPUTE(qa2, 2, prh.z * 0.25f)
  QA_COMPUTE(qa3, 3, prh.w * 0.25f)
#undef QA_COMPUTE

  // 4 independent streams
  float sm0 = -1e30f, sm1 = -1e30f, sm2 = -1e30f, sm3 = -1e30f;
  float ss0 = 0.f, ss1 = 0.f, ss2 = 0.f, ss3 = 0.f;
  float2 z = make_float2(0.f, 0.f);
  float2 a0t0=z,a0t1=z,a0t2=z,a0t3=z;
  float2 a1t0=z,a1t1=z,a1t2=z,a1t3=z;
  float2 a2t0=z,a2t1=z,a2t2=z,a2t3=z;
  float2 a3t0=z,a3t1=z,a3t2=z,a3t3=z;

#define PROC(S, KV, TY, VALID) { \
    int ty = (TY) & 3; \
    float kx = blo((KV).x), ky = bhi((KV).x); \
    float2 qat = (ty==0)?qa0:(ty==1)?qa1:(ty==2)?qa2:qa3; \
    float part = kx*qat.x + ky*qat.y; \
    part += __shfl_xor(part, 1); \
    part += __shfl_xor(part, 2); \
    part += __shfl_xor(part, 4); \
    float mn = (VALID) ? fmaxf(sm##S, part) : sm##S; \
    float sc  = __expf(sm##S - mn); \
    float wgt = (VALID) ? __expf(part - mn) : 0.f; \
    ss##S = ss##S * sc + wgt; \
    float vx = blo((KV).y), vy = bhi((KV).y); \
    float w0=(ty==0)?wgt:0.f, w1=(ty==1)?wgt:0.f, w2=(ty==2)?wgt:0.f, w3=(ty==3)?wgt:0.f; \
    a##S##t0.x = a##S##t0.x*sc + w0*vx; a##S##t0.y = a##S##t0.y*sc + w0*vy; \
    a##S##t1.x = a##S##t1.x*sc + w1*vx; a##S##t1.y = a##S##t1.y*sc + w1*vy; \
    a##S##t2.x = a##S##t2.x*sc + w2*vx; a##S##t2.y = a##S##t2.y*sc + w2*vy; \
    a##S##t3.x = a##S##t3.x*sc + w3*vx; a##S##t3.y = a##S##t3.y*sc + w3*vy; \
    sm##S = mn; }

  for (int b0 = o0; b0 < o1; b0 += 64) {
    int cnt = o1 - b0; if (cnt > 64) cnt = 64;
    int stv = est[b0 + l];          // est padded by 64 -> no guard needed
#define SLOT(I) (((I) < cnt) ? (I) : (cnt - 1))
    int t0 = __shfl(stv, SLOT(0)), t1 = __shfl(stv, SLOT(1));
    int t2 = __shfl(stv, SLOT(2)), t3 = __shfl(stv, SLOT(3));
    uint2 kv0 = kvb[(size_t)(t0 >> 2) * 64 + l];
    uint2 kv1 = kvb[(size_t)(t1 >> 2) * 64 + l];
    uint2 kv2 = kvb[(size_t)(t2 >> 2) * 64 + l];
    uint2 kv3 = kvb[(size_t)(t3 >> 2) * 64 + l];
    for (int i = 0; i < cnt; i += 4) {
      // prefetch next group (clamped slots re-read the just-fetched line: L1-hot)
      int n0 = __shfl(stv, SLOT(i+4)), n1 = __shfl(stv, SLOT(i+5));
      int n2 = __shfl(stv, SLOT(i+6)), n3 = __shfl(stv, SLOT(i+7));
      uint2 kn0 = kvb[(size_t)(n0 >> 2) * 64 + l];
      uint2 kn1 = kvb[(size_t)(n1 >> 2) * 64 + l];
      uint2 kn2 = kvb[(size_t)(n2 >> 2) * 64 + l];
      uint2 kn3 = kvb[(size_t)(n3 >> 2) * 64 + l];
      PROC(0, kv0, t0, true)
      PROC(1, kv1, t1, (i + 1) < cnt)
      PROC(2, kv2, t2, (i + 2) < cnt)
      PROC(3, kv3, t3, (i + 3) < cnt)
      t0 = n0; t1 = n1; t2 = n2; t3 = n3;
      kv0 = kn0; kv1 = kn1; kv2 = kn2; kv3 = kn3;
    }
#undef SLOT
  }
#undef PROC

  // merge 4 streams (flash-style)
  float M = fmaxf(fmaxf(sm0, sm1), fmaxf(sm2, sm3));
  float e0 = __expf(sm0 - M), e1 = __expf(sm1 - M);
  float e2 = __expf(sm2 - M), e3 = __expf(sm3 - M);
  float ssum = ss0 * e0 + ss1 * e1 + ss2 * e2 + ss3 * e3;
  float inv = (ssum > 0.f) ? 1.f / ssum : 0.f;
  float2 acc0, acc1, acc2, acc3;
  acc0.x = (a0t0.x*e0 + a1t0.x*e1 + a2t0.x*e2 + a3t0.x*e3) * inv;
  acc0.y = (a0t0.y*e0 + a1t0.y*e1 + a2t0.y*e2 + a3t0.y*e3) * inv;
  acc1.x = (a0t1.x*e0 + a1t1.x*e1 + a2t1.x*e2 + a3t1.x*e3) * inv;
  acc1.y = (a0t1.y*e0 + a1t1.y*e1 + a2t1.y*e2 + a3t1.y*e3) * inv;
  acc2.x = (a0t2.x*e0 + a1t2.x*e1 + a2t2.x*e2 + a3t2.x*e3) * inv;
  acc2.y = (a0t2.y*e0 + a1t2.y*e1 + a2t2.y*e2 + a3t2.y*e3) * inv;
  acc3.x = (a0t3.x*e0 + a1t3.x*e1 + a2t3.x*e2 + a3t3.x*e3) * inv;
  acc3.y = (a0t3.y*e0 + a1t3.y*e1 + a2t3.y*e2 + a3t3.y*e3) * inv;

  // stage per-ty accumulators (wave-private region; no barrier needed)
  ((float2*)&accs[w][0][0])[l] = acc0;
  ((float2*)&accs[w][1][0])[l] = acc1;
  ((float2*)&accs[w][2][0])[l] = acc2;
  ((float2*)&accs[w][3][0])[l] = acc3;

  float ox = 0.f, oy = 0.f;
#pragma unroll
  for (int ty = 0; ty < 4; ++ty) {
    const float4* AmR = (const float4*)(AmT + ((h * 4 + ty) * 16) * 16);
#pragma unroll
    for (int d4 = 0; d4 < 4; ++d4) {
      float4 ac = *((float4*)&accs[w][ty][h * 16 + d4 * 4]);
      float4 m0 = AmR[(2 * j) * 4 + d4];
      float4 m1 = AmR[(2 * j + 1) * 4 + d4];
      ox += m0.x * ac.x + m0.y * ac.y + m0.z * ac.z + m0.w * ac.w;
      oy += m1.x * ac.x + m1.y * ac.y + m1.z * ac.z + m1.w * ac.w;
    }
  }
  ((float2*)hb)[(size_t)n * 64 + l] = make_float2(ox, oy);
}

// ---- typed output projection + sigmoid-skip residual (in-place on x) -----
__global__ __launch_bounds__(256) void k_out(const float* __restrict__ hb,
                                             const float* __restrict__ Wa,
                                             const float* __restrict__ skipv,
                                             float* __restrict__ xio) {
  __shared__ float hs[32][128];
  int ty, base, nrows;
  seg_decode(blockIdx.x, ty, base, nrows);
  int t = threadIdx.x;
#pragma unroll
  for (int it = 0; it < 4; ++it) {
    int idx4 = t + it * 256;
    int row = idx4 >> 5, c4 = idx4 & 31;
    float4 val = make_float4(0.f, 0.f, 0.f, 0.f);
    if (row < nrows) val = ((const float4*)(hb + (size_t)(base + row) * INF))[c4];
    ((float4*)&hs[row][0])[c4] = val;
  }
  __syncthreads();
  int o = t & 127, g = t >> 7;
  float acc[16];
#pragma unroll
  for (int j = 0; j < 16; ++j) acc[j] = 0.f;
  const float* WA = Wa + ty * 16384;
  for (int i0 = 0; i0 < 32; ++i0) {
    float wa[4];
#pragma unroll
    for (int di = 0; di < 4; ++di) wa[di] = WA[(i0 * 4 + di) * 128 + o];
#pragma unroll
    for (int j = 0; j < 16; ++j) {
      float4 h4 = ((const float4*)&hs[g * 16 + j][0])[i0];
      acc[j] += h4.x * wa[0] + h4.y * wa[1] + h4.z * wa[2] + h4.w * wa[3];
    }
  }
  float alpha = 1.f / (1.f + __expf(-skipv[ty]));
  float beta = 1.f - alpha;
#pragma unroll
  for (int j = 0; j < 16; ++j) {
    int row = g * 16 + j;
    if (row < nrows) {
      size_t p = (size_t)(base + row) * INF + o;
      xio[p] = acc[j] * alpha + xio[p] * beta;
    }
  }
}

extern "C" void kernel_launch(void* const* d_in, const int* in_sizes, int n_in,
                              void* d_out, int out_size, void* d_ws, size_t ws_size,
                              hipStream_t stream) {
  const float* drug = (const float*)d_in[0];
  const float* dis  = (const float*)d_in[1];
  const float* prot = (const float*)d_in[2];
  const int* src    = (const int*)d_in[3];
  const int* dst    = (const int*)d_in[4];
  const int* etp    = (const int*)d_in[5];
  const float* Wk   = (const float*)d_in[6];
  const float* Wq   = (const float*)d_in[7];
  const float* Wv   = (const float*)d_in[8];
  const float* Wa   = (const float*)d_in[9];
  const float* rel_att = (const float*)d_in[10];
  const float* rel_msg = (const float*)d_in[11];
  const float* pri  = (const float*)d_in[12];
  const float* skip = (const float*)d_in[13];
  float* x = (float*)d_out;

  char* w = (char*)d_ws;
  uint2* kvb  = (uint2*)(w + 0);            // 25,600,000 B (50000 * 512)
  float* qb   = (float*)(w + 25600000);     // 25,600,000 B
  float* hb   = (float*)(w + 51200000);     // 25,600,000 B
  float* AmT  = (float*)(w + 76800000);     //     32,768 B
  int*   deg  = (int*)(w + 76832768);       //    200,000 B
  int*   off  = (int*)(w + 77032768);       //    200,004 B
  int*   cur  = (int*)(w + 77232772);       //    200,000 B
  int*   est  = (int*)(w + 77432772);       //  1,600,256 B (padded by 64)

  // x = concat(features)
  k_concat<<<6250, 256, 0, stream>>>(drug, dis, prot, x);

  // CSR by dst (edges constant across layers)
  hipMemsetAsync(deg, 0, N_NODE * sizeof(int), stream);
  hipMemsetAsync(est + N_EDGE, 0, 64 * sizeof(int), stream);
  k_count<<<(N_EDGE + 255) / 256, 256, 0, stream>>>(dst, deg);
  k_scan<<<1, 1024, 0, stream>>>(deg, off, cur);
  k_fill<<<(N_EDGE + 255) / 256, 256, 0, stream>>>(dst, src, etp, cur, est);

  // rel_msg transpose (constant across layers)
  k_trmsg<<<32, 256, 0, stream>>>(rel_msg, AmT);

  for (int layer = 0; layer < 2; ++layer) {
    k_qkv<<<NTILES, 256, 0, stream>>>(x, Wk, Wq, Wv, kvb, qb);
    k_fused<<<12500, 256, 0, stream>>>(kvb, qb, off, est, rel_att, AmT, pri, hb);
    k_out<<<NTILES, 256, 0, stream>>>(hb, Wa, skip, x);
  }
}

// Round 5
// 1020.432 us; speedup vs baseline: 1.1967x; 1.1967x over previous
//
#include <hip/hip_runtime.h>

#define N_NODE 50000
#define N_EDGE 400000
#define INF    128

// segment tiling (32 rows/tile), boundaries are compile-time: 10000 / 20000 / 50000
#define TILES0 313
#define TILES1 313
#define TILES2 938
#define NTILES 1564

#define FUSED_BLOCKS 1600   // persistent: 6.25 blocks/CU, 4 waves each

__device__ __forceinline__ void seg_decode(int b, int& ty, int& base, int& nrows) {
  if (b < TILES0)            { ty = 0; base = b * 32;                      nrows = 10000 - base; }
  else if (b < TILES0+TILES1){ ty = 1; base = 10000 + (b - TILES0) * 32;   nrows = 20000 - base; }
  else                       { ty = 2; base = 20000 + (b - TILES0-TILES1)*32; nrows = 50000 - base; }
  if (nrows > 32) nrows = 32;
}

__device__ __forceinline__ float blo(unsigned u) { return __uint_as_float(u << 16); }
__device__ __forceinline__ float bhi(unsigned u) { return __uint_as_float(u & 0xffff0000u); }
// pack two f32 -> bf16x2 (RNE), lo = even dim, hi = odd dim
__device__ __forceinline__ unsigned bpack(float lo, float hi) {
  unsigned a = __float_as_uint(lo), b = __float_as_uint(hi);
  a = (a + 0x7fffu + ((a >> 16) & 1u)) >> 16;
  b = (b + 0x7fffu + ((b >> 16) & 1u)) & 0xffff0000u;
  return a | b;
}

// ---- concat features into x (= d_out), grid-stride -----------------------
__global__ __launch_bounds__(256) void k_concat(const float* __restrict__ dr,
                                                const float* __restrict__ di,
                                                const float* __restrict__ pr,
                                                float* __restrict__ x) {
  for (int i = blockIdx.x * 256 + threadIdx.x; i < N_NODE * 32; i += 2048 * 256) {
    int row = i >> 5;
    float4 val;
    if (row < 10000)      val = ((const float4*)dr)[i];
    else if (row < 20000) val = ((const float4*)di)[i - 10000*32];
    else                  val = ((const float4*)pr)[i - 20000*32];
    ((float4*)x)[i] = val;
  }
}

// ---- CSR build -----------------------------------------------------------
__global__ __launch_bounds__(256) void k_count(const int* __restrict__ dst, int* __restrict__ deg) {
  int e = blockIdx.x * 256 + threadIdx.x;
  if (e < N_EDGE) atomicAdd(&deg[dst[e]], 1);
}

__global__ __launch_bounds__(1024) void k_scan(const int* __restrict__ deg,
                                               int* __restrict__ off, int* __restrict__ cur) {
  __shared__ int part[1024];
  int t = threadIdx.x;
  int c0 = t * 49;
  int c1 = c0 + 49; if (c1 > N_NODE) c1 = N_NODE;
  int s = 0;
  for (int i = c0; i < c1; ++i) s += deg[i];
  part[t] = s;
  __syncthreads();
  for (int ofs = 1; ofs < 1024; ofs <<= 1) {
    int v = (t >= ofs) ? part[t - ofs] : 0;
    __syncthreads();
    part[t] += v;
    __syncthreads();
  }
  int run = (t == 0) ? 0 : part[t - 1];
  for (int i = c0; i < c1; ++i) { off[i] = run; cur[i] = run; run += deg[i]; }
  if (t == 1023) off[N_NODE] = part[1023];
}

// writes combined edge record est[p] = (src<<2) | etype
__global__ __launch_bounds__(256) void k_fill(const int* __restrict__ dst,
                                              const int* __restrict__ src,
                                              const int* __restrict__ etp,
                                              int* __restrict__ cur, int* __restrict__ est) {
  int e = blockIdx.x * 256 + threadIdx.x;
  if (e < N_EDGE) {
    int p = atomicAdd(&cur[dst[e]], 1);
    est[p] = (src[e] << 2) | etp[e];
  }
}

// ---- transpose rel_msg: AmT[h][ty][do][di] = rel_msg[h][ty][di][do] ------
__global__ __launch_bounds__(256) void k_trmsg(const float* __restrict__ rm,
                                               float* __restrict__ AmT) {
  int i = blockIdx.x * 256 + threadIdx.x;   // 8192 total
  int di = i & 15, doo = (i >> 4) & 15, ty = (i >> 8) & 3, hh = i >> 10;
  AmT[i] = rm[((hh * 4 + ty) * 16 + di) * 16 + doo];
}

// ---- typed K/Q/V projection; k,v packed interleaved bf16 -----------------
// kvb[n] = 64 x uint2 : elem l = { bf16x2(k[2l],k[2l+1]), bf16x2(v[2l],v[2l+1]) }
__global__ __launch_bounds__(256) void k_qkv(const float* __restrict__ x,
                                             const float* __restrict__ Wk,
                                             const float* __restrict__ Wq,
                                             const float* __restrict__ Wv,
                                             uint2* __restrict__ kvb,
                                             float* __restrict__ qb) {
  __shared__ float xs[32][128];
  int ty, base, nrows;
  seg_decode(blockIdx.x, ty, base, nrows);
  int t = threadIdx.x;
#pragma unroll
  for (int it = 0; it < 4; ++it) {
    int idx4 = t + it * 256;
    int row = idx4 >> 5, c4 = idx4 & 31;
    float4 val = make_float4(0.f, 0.f, 0.f, 0.f);
    if (row < nrows) val = ((const float4*)(x + (size_t)(base + row) * INF))[c4];
    ((float4*)&xs[row][0])[c4] = val;
  }
  __syncthreads();
  int o = t & 127, g = t >> 7;
  float ak[16], aq[16], av[16];
#pragma unroll
  for (int j = 0; j < 16; ++j) { ak[j] = 0.f; aq[j] = 0.f; av[j] = 0.f; }
  const float* WK = Wk + ty * 16384;
  const float* WQ = Wq + ty * 16384;
  const float* WV = Wv + ty * 16384;
  for (int i0 = 0; i0 < 32; ++i0) {
    float wk[4], wq[4], wv[4];
#pragma unroll
    for (int di = 0; di < 4; ++di) {
      int i = i0 * 4 + di;
      wk[di] = WK[i * 128 + o];
      wq[di] = WQ[i * 128 + o];
      wv[di] = WV[i * 128 + o];
    }
#pragma unroll
    for (int j = 0; j < 16; ++j) {
      float4 x4 = ((const float4*)&xs[g * 16 + j][0])[i0];
      ak[j] += x4.x * wk[0] + x4.y * wk[1] + x4.z * wk[2] + x4.w * wk[3];
      aq[j] += x4.x * wq[0] + x4.y * wq[1] + x4.z * wq[2] + x4.w * wq[3];
      av[j] += x4.x * wv[0] + x4.y * wv[1] + x4.z * wv[2] + x4.w * wv[3];
    }
  }
#pragma unroll
  for (int j = 0; j < 16; ++j) {
    int row = g * 16 + j;
    float akn = __shfl_xor(ak[j], 1);   // neighbor column value (same row)
    float avn = __shfl_xor(av[j], 1);
    if (row < nrows) {
      size_t p = (size_t)(base + row);
      qb[p * INF + o] = aq[j];
      if ((o & 1) == 0)
        kvb[p * 64 + (o >> 1)] = make_uint2(bpack(ak[j], akn), bpack(av[j], avn));
    }
  }
}

// ---- fused attention: logits + edge-softmax + aggregation ---------------
// PERSISTENT grid-stride: FUSED_BLOCKS blocks x 4 waves, each wave loops over
// nodes n = bid*4+w, += FUSED_BLOCKS*4. 2 independent online-softmax streams.
__global__ __launch_bounds__(256) void k_fused(const uint2* __restrict__ kvb,
                                               const float* __restrict__ qb,
                                               const int* __restrict__ off,
                                               const int* __restrict__ est,
                                               const float* __restrict__ rel_att,
                                               const float* __restrict__ AmT,
                                               const float* __restrict__ pri,
                                               float* __restrict__ hb) {
  __shared__ float accs[4][4][128];
  int w = threadIdx.x >> 6, l = threadIdx.x & 63;
  int h = l >> 3, j = l & 7;
  float4 prh = ((const float4*)pri)[h];

  for (int n = blockIdx.x * 4 + w; n < N_NODE; n += FUSED_BLOCKS * 4) {
    int o0 = off[n], o1 = off[n + 1];

    // q head fragment direct from global (L1 broadcast across the 8 lanes/head)
    const float4* q4p = (const float4*)(qb + (size_t)n * INF);
    float4 q40 = q4p[h * 4 + 0], q41 = q4p[h * 4 + 1];
    float4 q42 = q4p[h * 4 + 2], q43 = q4p[h * 4 + 3];

    // qa[ty] = (pri[h,ty]/4) * rel_att[h,ty] . q[n]  for this lane's 2 dims
    float2 qa0, qa1, qa2, qa3;
#define QA_COMPUTE(QA, TY, PRSC) { \
    float ax = 0.f, ay = 0.f; \
    const float4* Ar = (const float4*)(rel_att + ((h * 4 + (TY)) * 16) * 16); \
    float4 a0, a1; \
    a0 = Ar[(2*j)*4+0]; a1 = Ar[(2*j+1)*4+0]; \
    ax += a0.x*q40.x + a0.y*q40.y + a0.z*q40.z + a0.w*q40.w; \
    ay += a1.x*q40.x + a1.y*q40.y + a1.z*q40.z + a1.w*q40.w; \
    a0 = Ar[(2*j)*4+1]; a1 = Ar[(2*j+1)*4+1]; \
    ax += a0.x*q41.x + a0.y*q41.y + a0.z*q41.z + a0.w*q41.w; \
    ay += a1.x*q41.x + a1.y*q41.y + a1.z*q41.z + a1.w*q41.w; \
    a0 = Ar[(2*j)*4+2]; a1 = Ar[(2*j+1)*4+2]; \
    ax += a0.x*q42.x + a0.y*q42.y + a0.z*q42.z + a0.w*q42.w; \
    ay += a1.x*q42.x + a1.y*q42.y + a1.z*q42.z + a1.w*q42.w; \
    a0 = Ar[(2*j)*4+3]; a1 = Ar[(2*j+1)*4+3]; \
    ax += a0.x*q43.x + a0.y*q43.y + a0.z*q43.z + a0.w*q43.w; \
    ay += a1.x*q43.x + a1.y*q43.y + a1.z*q43.z + a1.w*q43.w; \
    QA = make_float2(ax * (PRSC), ay * (PRSC)); }
    QA_COMPUTE(qa0, 0, prh.x * 0.25f)
    QA_COMPUTE(qa1, 1, prh.y * 0.25f)
    QA_COMPUTE(qa2, 2, prh.z * 0.25f)
    QA_COMPUTE(qa3, 3, prh.w * 0.25f)
#undef QA_COMPUTE

    // 2 independent streams
    float sm0 = -1e30f, sm1 = -1e30f;
    float ss0 = 0.f, ss1 = 0.f;
    float2 z = make_float2(0.f, 0.f);
    float2 a0t0=z,a0t1=z,a0t2=z,a0t3=z;
    float2 a1t0=z,a1t1=z,a1t2=z,a1t3=z;

#define PROC(S, KV, TY, VALID) { \
    int ty = (TY) & 3; \
    float kx = blo((KV).x), ky = bhi((KV).x); \
    float2 qat = (ty==0)?qa0:(ty==1)?qa1:(ty==2)?qa2:qa3; \
    float part = kx*qat.x + ky*qat.y; \
    part += __shfl_xor(part, 1); \
    part += __shfl_xor(part, 2); \
    part += __shfl_xor(part, 4); \
    float mn = (VALID) ? fmaxf(sm##S, part) : sm##S; \
    float sc  = __expf(sm##S - mn); \
    float wgt = (VALID) ? __expf(part - mn) : 0.f; \
    ss##S = ss##S * sc + wgt; \
    float vx = blo((KV).y), vy = bhi((KV).y); \
    float w0=(ty==0)?wgt:0.f, w1=(ty==1)?wgt:0.f, w2=(ty==2)?wgt:0.f, w3=(ty==3)?wgt:0.f; \
    a##S##t0.x = a##S##t0.x*sc + w0*vx; a##S##t0.y = a##S##t0.y*sc + w0*vy; \
    a##S##t1.x = a##S##t1.x*sc + w1*vx; a##S##t1.y = a##S##t1.y*sc + w1*vy; \
    a##S##t2.x = a##S##t2.x*sc + w2*vx; a##S##t2.y = a##S##t2.y*sc + w2*vy; \
    a##S##t3.x = a##S##t3.x*sc + w3*vx; a##S##t3.y = a##S##t3.y*sc + w3*vy; \
    sm##S = mn; }

    for (int b0 = o0; b0 < o1; b0 += 64) {
      int cnt = o1 - b0; if (cnt > 64) cnt = 64;
      int stv = est[b0 + l];          // est padded by 64 -> no guard needed
      int t0 = __shfl(stv, 0);
      int t1 = __shfl(stv, 1 < cnt ? 1 : 0);
      uint2 kv0 = kvb[(size_t)(t0 >> 2) * 64 + l];
      uint2 kv1 = kvb[(size_t)(t1 >> 2) * 64 + l];
      for (int i = 0; i < cnt; i += 2) {
        bool more = (i + 2) < cnt;        // wave-uniform
        int n0 = 0, n1 = 0; uint2 kn0, kn1;
        if (more) {
          n0 = __shfl(stv, i + 2);
          n1 = __shfl(stv, (i + 3) < cnt ? (i + 3) : (i + 2));
          kn0 = kvb[(size_t)(n0 >> 2) * 64 + l];
          kn1 = kvb[(size_t)(n1 >> 2) * 64 + l];
        }
        PROC(0, kv0, t0, true)
        PROC(1, kv1, t1, (i + 1) < cnt)
        if (more) { t0 = n0; t1 = n1; kv0 = kn0; kv1 = kn1; }
      }
    }
#undef PROC

    // merge 2 streams
    float M = fmaxf(sm0, sm1);
    float e0 = __expf(sm0 - M), e1 = __expf(sm1 - M);
    float ssum = ss0 * e0 + ss1 * e1;
    float inv = (ssum > 0.f) ? 1.f / ssum : 0.f;
    float2 acc0, acc1, acc2, acc3;
    acc0.x = (a0t0.x*e0 + a1t0.x*e1) * inv; acc0.y = (a0t0.y*e0 + a1t0.y*e1) * inv;
    acc1.x = (a0t1.x*e0 + a1t1.x*e1) * inv; acc1.y = (a0t1.y*e0 + a1t1.y*e1) * inv;
    acc2.x = (a0t2.x*e0 + a1t2.x*e1) * inv; acc2.y = (a0t2.y*e0 + a1t2.y*e1) * inv;
    acc3.x = (a0t3.x*e0 + a1t3.x*e1) * inv; acc3.y = (a0t3.y*e0 + a1t3.y*e1) * inv;

    // stage per-ty accumulators (wave-private region; no barrier needed)
    ((float2*)&accs[w][0][0])[l] = acc0;
    ((float2*)&accs[w][1][0])[l] = acc1;
    ((float2*)&accs[w][2][0])[l] = acc2;
    ((float2*)&accs[w][3][0])[l] = acc3;

    float ox = 0.f, oy = 0.f;
#pragma unroll
    for (int ty = 0; ty < 4; ++ty) {
      const float4* AmR = (const float4*)(AmT + ((h * 4 + ty) * 16) * 16);
#pragma unroll
      for (int d4 = 0; d4 < 4; ++d4) {
        float4 ac = *((float4*)&accs[w][ty][h * 16 + d4 * 4]);
        float4 m0 = AmR[(2 * j) * 4 + d4];
        float4 m1 = AmR[(2 * j + 1) * 4 + d4];
        ox += m0.x * ac.x + m0.y * ac.y + m0.z * ac.z + m0.w * ac.w;
        oy += m1.x * ac.x + m1.y * ac.y + m1.z * ac.z + m1.w * ac.w;
      }
    }
    ((float2*)hb)[(size_t)n * 64 + l] = make_float2(ox, oy);
  }
}

// ---- typed output projection + sigmoid-skip residual (in-place on x) -----
__global__ __launch_bounds__(256) void k_out(const float* __restrict__ hb,
                                             const float* __restrict__ Wa,
                                             const float* __restrict__ skipv,
                                             float* __restrict__ xio) {
  __shared__ float hs[32][128];
  int ty, base, nrows;
  seg_decode(blockIdx.x, ty, base, nrows);
  int t = threadIdx.x;
#pragma unroll
  for (int it = 0; it < 4; ++it) {
    int idx4 = t + it * 256;
    int row = idx4 >> 5, c4 = idx4 & 31;
    float4 val = make_float4(0.f, 0.f, 0.f, 0.f);
    if (row < nrows) val = ((const float4*)(hb + (size_t)(base + row) * INF))[c4];
    ((float4*)&hs[row][0])[c4] = val;
  }
  __syncthreads();
  int o = t & 127, g = t >> 7;
  float acc[16];
#pragma unroll
  for (int j = 0; j < 16; ++j) acc[j] = 0.f;
  const float* WA = Wa + ty * 16384;
  for (int i0 = 0; i0 < 32; ++i0) {
    float wa[4];
#pragma unroll
    for (int di = 0; di < 4; ++di) wa[di] = WA[(i0 * 4 + di) * 128 + o];
#pragma unroll
    for (int j = 0; j < 16; ++j) {
      float4 h4 = ((const float4*)&hs[g * 16 + j][0])[i0];
      acc[j] += h4.x * wa[0] + h4.y * wa[1] + h4.z * wa[2] + h4.w * wa[3];
    }
  }
  float alpha = 1.f / (1.f + __expf(-skipv[ty]));
  float beta = 1.f - alpha;
#pragma unroll
  for (int j = 0; j < 16; ++j) {
    int row = g * 16 + j;
    if (row < nrows) {
      size_t p = (size_t)(base + row) * INF + o;
      xio[p] = acc[j] * alpha + xio[p] * beta;
    }
  }
}

extern "C" void kernel_launch(void* const* d_in, const int* in_sizes, int n_in,
                              void* d_out, int out_size, void* d_ws, size_t ws_size,
                              hipStream_t stream) {
  const float* drug = (const float*)d_in[0];
  const float* dis  = (const float*)d_in[1];
  const float* prot = (const float*)d_in[2];
  const int* src    = (const int*)d_in[3];
  const int* dst    = (const int*)d_in[4];
  const int* etp    = (const int*)d_in[5];
  const float* Wk   = (const float*)d_in[6];
  const float* Wq   = (const float*)d_in[7];
  const float* Wv   = (const float*)d_in[8];
  const float* Wa   = (const float*)d_in[9];
  const float* rel_att = (const float*)d_in[10];
  const float* rel_msg = (const float*)d_in[11];
  const float* pri  = (const float*)d_in[12];
  const float* skip = (const float*)d_in[13];
  float* x = (float*)d_out;

  char* w = (char*)d_ws;
  uint2* kvb  = (uint2*)(w + 0);            // 25,600,000 B (50000 * 512)
  float* qb   = (float*)(w + 25600000);     // 25,600,000 B
  float* hb   = (float*)(w + 51200000);     // 25,600,000 B
  float* AmT  = (float*)(w + 76800000);     //     32,768 B
  int*   deg  = (int*)(w + 76832768);       //    200,000 B
  int*   off  = (int*)(w + 77032768);       //    200,004 B
  int*   cur  = (int*)(w + 77232772);       //    200,000 B
  int*   est  = (int*)(w + 77432772);       //  1,600,256 B (padded by 64)

  // x = concat(features)
  k_concat<<<2048, 256, 0, stream>>>(drug, dis, prot, x);

  // CSR by dst (edges constant across layers)
  hipMemsetAsync(deg, 0, N_NODE * sizeof(int), stream);
  hipMemsetAsync(est + N_EDGE, 0, 64 * sizeof(int), stream);
  k_count<<<(N_EDGE + 255) / 256, 256, 0, stream>>>(dst, deg);
  k_scan<<<1, 1024, 0, stream>>>(deg, off, cur);
  k_fill<<<(N_EDGE + 255) / 256, 256, 0, stream>>>(dst, src, etp, cur, est);

  // rel_msg transpose (constant across layers)
  k_trmsg<<<32, 256, 0, stream>>>(rel_msg, AmT);

  for (int layer = 0; layer < 2; ++layer) {
    k_qkv<<<NTILES, 256, 0, stream>>>(x, Wk, Wq, Wv, kvb, qb);
    k_fused<<<FUSED_BLOCKS, 256, 0, stream>>>(kvb, qb, off, est, rel_att, AmT, pri, hb);
    k_out<<<NTILES, 256, 0, stream>>>(hb, Wa, skip, x);
  }
}